// Round 14
// baseline (386.600 us; speedup 1.0000x reference)
//
#include <hip/hip_runtime.h>
#include <math.h>

#define NN 8192
#define CC 256
#define OO 64
#define JW 8      // j's per wave in k_rank
// instrumentation multipliers (round 14): per-dispatch time = REP * T_kernel
#define REP_GEMM  12
#define REP_RANK  8
#define REP_DT    16
#define REP_MERGE 12

// ============ K1: GEMM (W1 + x staged in LDS) + f1/f2 + exp tables + sortable keys ============
__global__ __launch_bounds__(256) void k_gemm(
    const float* __restrict__ x, const float* __restrict__ W1,
    const float* __restrict__ b1, const float* __restrict__ a1,
    const float* __restrict__ ba1, const float* __restrict__ a2,
    const float* __restrict__ ba2,
    float* __restrict__ seq,
    float* __restrict__ f1, float* __restrict__ f2,
    float* __restrict__ E1, float* __restrict__ E1s,
    float* __restrict__ eF2, float* __restrict__ eF2s,
    unsigned long long* __restrict__ keys /* [2][NN] */)
{
  __shared__ float w_lds[64][66];
  __shared__ float x_lds[16][256];
  const int t = threadIdx.x;
  const int p = t & 31;             // col pair: o = 2p, 2p+1
  const int g = t >> 5;             // 0..7 row group
  const int r0 = blockIdx.x*16 + g*2;
  const int r1 = r0 + 1;
  for (int rep = 0; rep < REP_GEMM; ++rep) {
  __syncthreads();
  // stage 16 x-rows (coalesced)
  {
    const float4* xg = (const float4*)(x + (size_t)blockIdx.x*16*CC);
#pragma unroll
    for (int q = t; q < 1024; q += 256)
      ((float4*)x_lds)[q] = xg[q];
  }
  float c00 = 0.f, c01 = 0.f, c10 = 0.f, c11 = 0.f;
  for (int ct = 0; ct < 4; ++ct) {
    __syncthreads();
    for (int idx = t; idx < 4096; idx += 256) {
      const int o = idx >> 6, cc = idx & 63;
      w_lds[cc][o] = W1[o*CC + ct*64 + cc];
    }
    __syncthreads();
    const float* xr0 = &x_lds[g*2][ct*64];
    const float* xr1 = &x_lds[g*2+1][ct*64];
#pragma unroll 4
    for (int c = 0; c < 64; c += 4) {
      const float4 xa = *(const float4*)(xr0 + c);
      const float4 xb = *(const float4*)(xr1 + c);
      const float2 w0 = *(const float2*)&w_lds[c+0][2*p];
      const float2 w1 = *(const float2*)&w_lds[c+1][2*p];
      const float2 w2 = *(const float2*)&w_lds[c+2][2*p];
      const float2 w3 = *(const float2*)&w_lds[c+3][2*p];
      c00 = fmaf(xa.x, w0.x, c00); c00 = fmaf(xa.y, w1.x, c00);
      c00 = fmaf(xa.z, w2.x, c00); c00 = fmaf(xa.w, w3.x, c00);
      c01 = fmaf(xa.x, w0.y, c01); c01 = fmaf(xa.y, w1.y, c01);
      c01 = fmaf(xa.z, w2.y, c01); c01 = fmaf(xa.w, w3.y, c01);
      c10 = fmaf(xb.x, w0.x, c10); c10 = fmaf(xb.y, w1.x, c10);
      c10 = fmaf(xb.z, w2.x, c10); c10 = fmaf(xb.w, w3.x, c10);
      c11 = fmaf(xb.x, w0.y, c11); c11 = fmaf(xb.y, w1.y, c11);
      c11 = fmaf(xb.z, w2.y, c11); c11 = fmaf(xb.w, w3.y, c11);
    }
  }
  const float2 B2 = *(const float2*)&b1[2*p];
  const float v00 = c00 + B2.x, v01 = c01 + B2.y;
  const float v10 = c10 + B2.x, v11 = c11 + B2.y;
  *(float2*)&seq[(size_t)r0*OO + 2*p] = make_float2(v00, v01);
  *(float2*)&seq[(size_t)r1*OO + 2*p] = make_float2(v10, v11);
  const float2 A1 = *(const float2*)&a1[2*p];
  const float2 A2 = *(const float2*)&a2[2*p];
  float p1_0 = v00*A1.x + v01*A1.y;
  float p2_0 = v00*A2.x + v01*A2.y;
  float p1_1 = v10*A1.x + v11*A1.y;
  float p2_1 = v10*A2.x + v11*A2.y;
#pragma unroll
  for (int d = 1; d < 32; d <<= 1) {
    p1_0 += __shfl_xor(p1_0, d, 64);
    p2_0 += __shfl_xor(p2_0, d, 64);
    p1_1 += __shfl_xor(p1_1, d, 64);
    p2_1 += __shfl_xor(p2_1, d, 64);
  }
  if (p == 0) {
    const float bba1 = ba1[0], bba2 = ba2[0];
    const float t1a = p1_0 + bba1, t2a = p2_0 + bba2;
    const float t1b = p1_1 + bba1, t2b = p2_1 + bba2;
    f1[r0] = t1a; E1[r0] = expf(t1a); E1s[r0] = expf(0.01f*t1a);
    f2[r0] = t2a; eF2[r0] = expf(t2a); eF2s[r0] = expf(0.01f*t2a);
    f1[r1] = t1b; E1[r1] = expf(t1b); E1s[r1] = expf(0.01f*t1b);
    f2[r1] = t2b; eF2[r1] = expf(t2b); eF2s[r1] = expf(0.01f*t2b);
    unsigned u;
    u = __float_as_uint(t1a); u = (u & 0x80000000u) ? ~u : (u | 0x80000000u);
    keys[r0] = ((unsigned long long)u << 32) | (unsigned)r0;
    u = __float_as_uint(t1b); u = (u & 0x80000000u) ? ~u : (u | 0x80000000u);
    keys[r1] = ((unsigned long long)u << 32) | (unsigned)r1;
    u = __float_as_uint(t2a); u = (u & 0x80000000u) ? ~u : (u | 0x80000000u);
    keys[NN + r0] = ((unsigned long long)u << 32) | (unsigned)r0;
    u = __float_as_uint(t2b); u = (u & 0x80000000u) ? ~u : (u | 0x80000000u);
    keys[NN + r1] = ((unsigned long long)u << 32) | (unsigned)r1;
  }
  }  // rep
}

// ============ K2: rank counting from LDS-staged keys + sorted scatters (+inv1) ============
__global__ __launch_bounds__(512) void k_rank(
    const unsigned long long* __restrict__ keys,
    const float* __restrict__ f1, const float* __restrict__ E1,
    const float* __restrict__ E1s, const float* __restrict__ f2,
    const float* __restrict__ eF2, const float* __restrict__ eF2s,
    float* __restrict__ s1, float* __restrict__ se1, float* __restrict__ se1s,
    int* __restrict__ inv1,
    float* __restrict__ f2s, float* __restrict__ eF2srt,
    float* __restrict__ eF2ssrt, int* __restrict__ inv)
{
  __shared__ unsigned long long skl[NN];   // 64 KB
  const int t = threadIdx.x;
  const int lane = t & 63, wv = t >> 6;    // 8 waves
  const int gw = blockIdx.x*8 + wv;        // 0..2047
  const int bj = gw*JW;
  const int arr = bj >> 13;                // uniform per block (64-j aligned)
  const int jb = bj & (NN-1);
  const unsigned long long* kb = keys + ((size_t)arr << 13);
  for (int rep = 0; rep < REP_RANK; ++rep) {
  __syncthreads();
  for (int q = t; q < NN/2; q += 512)
    ((ulonglong2*)skl)[q] = ((const ulonglong2*)kb)[q];
  __syncthreads();
  unsigned long long K[JW];
#pragma unroll
  for (int q = 0; q < JW; ++q) {
    const unsigned long long kk = skl[jb + q];
    const unsigned lo = __builtin_amdgcn_readfirstlane((unsigned)kk);
    const unsigned hi = __builtin_amdgcn_readfirstlane((unsigned)(kk >> 32));
    K[q] = ((unsigned long long)hi << 32) | lo;
  }
  int cnt[JW];
#pragma unroll
  for (int q = 0; q < JW; ++q) cnt[q] = 0;
#pragma unroll 4
  for (int c = 0; c < NN/64; ++c) {
    const unsigned long long sk = skl[c*64 + lane];
#pragma unroll
    for (int q = 0; q < JW; ++q)
      cnt[q] += (sk < K[q]) ? 1 : 0;
  }
#pragma unroll
  for (int q = 0; q < JW; ++q) {
    int r = cnt[q];
#pragma unroll
    for (int d = 1; d < 64; d <<= 1) r += __shfl_xor(r, d, 64);
    if (lane == 0) {
      const int i = jb + q;
      if (arr == 0) {
        s1[r] = f1[i]; se1[r] = E1[i]; se1s[r] = E1s[i]; inv1[r] = i;
      } else {
        inv[r] = i; f2s[r] = f2[i]; eF2srt[r] = eF2[i]; eF2ssrt[r] = eF2s[i];
      }
    }
  }
  }  // rep
}

// ============ K3: D-factors + kpos (LDS bsearch) + TU/TV chunk totals ============
__global__ __launch_bounds__(1024) void k_DT(
    const float* __restrict__ se1, const float* __restrict__ se1s,
    const float* __restrict__ s1g,
    const float* __restrict__ f2s, const float* __restrict__ eF2srt,
    const float* __restrict__ eF2ssrt, const int* __restrict__ inv,
    const float* __restrict__ seq,
    float* __restrict__ Bs, float* __restrict__ Es,
    int* __restrict__ kpos, float* __restrict__ TU, float* __restrict__ TV)
{
  __shared__ float s1l[NN];          // 32 KB (sorted f1)
  __shared__ float f2sl[NN];         // 32 KB (sorted f2)
  __shared__ float csA[256], csB[256];
  __shared__ float csEA[257], csEB[257];
  __shared__ float wsA[4], wsB[4];
  __shared__ float bsl[32], esl[32];
  __shared__ float redU[16][64], redV[16][64];
  const int t = threadIdx.x;
  const int b = blockIdx.x;
  const int wv = t >> 6, lane = t & 63;
  for (int rep = 0; rep < REP_DT; ++rep) {
  __syncthreads();
  const float4 a0 = ((const float4*)se1 )[t*2];
  const float4 a1v = ((const float4*)se1 )[t*2+1];
  const float4 b0 = ((const float4*)se1s)[t*2];
  const float4 b1v = ((const float4*)se1s)[t*2+1];
  ((float4*)s1l)[t*2]   = ((const float4*)s1g)[t*2];
  ((float4*)s1l)[t*2+1] = ((const float4*)s1g)[t*2+1];
  ((float4*)f2sl)[t*2]   = ((const float4*)f2s)[t*2];
  ((float4*)f2sl)[t*2+1] = ((const float4*)f2s)[t*2+1];
  float sa = ((a0.x+a0.y)+(a0.z+a0.w)) + ((a1v.x+a1v.y)+(a1v.z+a1v.w));
  float sb = ((b0.x+b0.y)+(b0.z+b0.w)) + ((b1v.x+b1v.y)+(b1v.z+b1v.w));
  sa += __shfl_xor(sa, 1, 64); sb += __shfl_xor(sb, 1, 64);
  sa += __shfl_xor(sa, 2, 64); sb += __shfl_xor(sb, 2, 64);
  if ((t & 3) == 0) { csA[t>>2] = sa; csB[t>>2] = sb; }   // chunk(32) sums
  __syncthreads();
  // 4-wave shfl scan of 256 chunk sums
  if (t < 256) {
    float a = csA[t], bv = csB[t];
#pragma unroll
    for (int d = 1; d < 64; d <<= 1) {
      const float ua = __shfl_up(a, d, 64);
      const float ub = __shfl_up(bv, d, 64);
      if (lane >= d) { a += ua; bv += ub; }
    }
    csA[t] = a; csB[t] = bv;
    if (lane == 63) { wsA[wv] = a; wsB[wv] = bv; }
  }
  __syncthreads();
  if (t < 256) {
    float baseA = 0.f, baseB = 0.f;
    for (int q = 0; q < wv; ++q) { baseA += wsA[q]; baseB += wsB[q]; }
    csEA[t+1] = csA[t] + baseA;
    csEB[t+1] = csB[t] + baseB;
    if (t == 0) { csEA[0] = 0.f; csEB[0] = 0.f; }
  }
  __syncthreads();
  const int half = lane >> 5, m = lane & 31;
  // --- D part ---
  {
    const int kk = b*32 + 2*wv + half;
    const float tgt = -f2sl[kk];
    int pos = 0;
#pragma unroll
    for (int s = NN; s; s >>= 1) {
      const int c = pos + s;
      if (c <= NN && s1l[c-1] < tgt) pos = c;
    }
    const int base = pos & ~31, cn = pos & 31;
    float ta = 0.f, tb = 0.f;
    if (m < cn) { ta = se1[base+m]; tb = se1s[base+m]; }
#pragma unroll
    for (int d = 1; d < 32; d <<= 1) {
      ta += __shfl_xor(ta, d, 64);
      tb += __shfl_xor(tb, d, 64);
    }
    if (m == 0) {
      const float PreA = csEA[pos>>5] + ta;
      const float PreB = csEB[pos>>5] + tb;
      const float T1 = csEA[256];
      const float e2 = eF2srt[kk], e2s = eF2ssrt[kk];
      const float D = fmaf(T1 - PreA, e2, PreB * e2s);
      const float bsv = e2 / D, esv = e2s / D;
      Bs[kk] = bsv; Es[kk] = esv;
      bsl[2*wv + half] = bsv; esl[2*wv + half] = esv;
    }
  }
  // --- kpos: kpos[r] = #{ f2 < -s1[r] } via binary search in LDS sorted f2 ---
  if (t < 32) {
    const int r = b*32 + t;
    const float tgt = -s1l[r];
    int pos = 0;
#pragma unroll
    for (int s = NN; s; s >>= 1) {
      const int c = pos + s;
      if (c <= NN && f2sl[c-1] < tgt) pos = c;
    }
    kpos[r] = pos;
  }
  __syncthreads();
  // --- TU/TV: chunk b column totals from LDS factors ---
  {
    const int kk0 = b*32 + 2*wv, kk1 = kk0 + 1;
    const float s0v = seq[(size_t)inv[kk0]*OO + lane];
    const float s1v = seq[(size_t)inv[kk1]*OO + lane];
    redU[wv][lane] = bsl[2*wv]*s0v + bsl[2*wv+1]*s1v;
    redV[wv][lane] = esl[2*wv]*s0v + esl[2*wv+1]*s1v;
  }
  __syncthreads();
  if (wv == 0) {
    float r = 0.f;
#pragma unroll
    for (int q = 0; q < 16; ++q) r += redU[q][lane];
    TU[b*64 + lane] = r;
  } else if (wv == 1) {
    float r = 0.f;
#pragma unroll
    for (int q = 0; q < 16; ++q) r += redV[q][lane];
    TV[b*64 + lane] = r;
  }
  }  // rep
}

// ============ K4: merged prefix + output (no PU/PV tables), 1024 threads ============
__global__ __launch_bounds__(1024) void k_merge(
    const int* __restrict__ kpos, const int* __restrict__ inv,
    const int* __restrict__ inv1,
    const float* __restrict__ se1, const float* __restrict__ se1s,
    const float* __restrict__ Bs, const float* __restrict__ Es,
    const float* __restrict__ seq,
    const float* __restrict__ TU, const float* __restrict__ TV,
    float* __restrict__ out)
{
  __shared__ int kposl[NN];                    // 32 KB
  __shared__ float pu[33][64], pv[33][64];     // 16.5 KB
  __shared__ float rA[16][64], rB[16][64], rC[16][64];
  __shared__ int bnd[2];
  const int t = threadIdx.x, lane = t & 63, wv = t >> 6, b = blockIdx.x;
  for (int rep = 0; rep < REP_MERGE; ++rep) {
  __syncthreads();
  for (int q = t; q < NN/4; q += 1024)
    ((int4*)kposl)[q] = ((const int4*)kpos)[q];
  // base (chunks < b) and grand total of TU; base of TV — split over 16 waves
  float pbu = 0.f, pbv = 0.f, ptu = 0.f;
  for (int c = wv; c < 256; c += 16) {
    const float tu = TU[c*64 + lane], tv = TV[c*64 + lane];
    ptu += tu;
    if (c < b) { pbu += tu; pbv += tv; }
  }
  rA[wv][lane] = pbu; rB[wv][lane] = pbv; rC[wv][lane] = ptu;
  // stage scaled rows (16 waves x 2 rows, parallel gathers)
  {
    const int kk0 = b*32 + 2*wv, kk1 = kk0 + 1;
    const float sv0 = seq[(size_t)inv[kk0]*OO + lane];
    const float sv1 = seq[(size_t)inv[kk1]*OO + lane];
    pu[2*wv+1][lane] = Bs[kk0]*sv0; pv[2*wv+1][lane] = Es[kk0]*sv0;
    pu[2*wv+2][lane] = Bs[kk1]*sv1; pv[2*wv+2][lane] = Es[kk1]*sv1;
  }
  if (wv == 0) { pu[0][lane] = 0.f; pv[0][lane] = 0.f; }
  __syncthreads();
  if (t == 0) {   // emit range boundaries in descending kposl
    const int hi = 32*b + 32 + (b == 255 ? 1 : 0);
    int pos = 0;
    for (int s = NN; s; s >>= 1) { const int c = pos+s; if (c <= NN && kposl[c-1] >= hi) pos = c; }
    bnd[0] = pos;
    pos = 0;
    const int lo = 32*b;
    for (int s = NN; s; s >>= 1) { const int c = pos+s; if (c <= NN && kposl[c-1] >= lo) pos = c; }
    bnd[1] = pos;
  }
  float base_u = 0.f, base_v = 0.f, utot = 0.f;
#pragma unroll
  for (int q = 0; q < 16; ++q) {
    base_u += rA[q][lane]; base_v += rB[q][lane]; utot += rC[q][lane];
  }
  // Hillis-Steele over rows 1..32 (2 rows per thread-slice)
  for (int d = 1; d < 32; d <<= 1) {
    const int rowA = wv + 1;        // rows 1..16
    const int rowB = wv + 17;       // rows 17..32
    const int srcA = rowA - d, srcB = rowB - d;
    const float aA = (srcA >= 0) ? pu[srcA][lane] : 0.f;
    const float vA = (srcA >= 0) ? pv[srcA][lane] : 0.f;
    const float aB = (srcB >= 0) ? pu[srcB][lane] : 0.f;
    const float vB = (srcB >= 0) ? pv[srcB][lane] : 0.f;
    __syncthreads();
    pu[rowA][lane] += aA; pv[rowA][lane] += vA;
    pu[rowB][lane] += aB; pv[rowB][lane] += vB;
    __syncthreads();
  }
  // parallel emits
  const int r0 = bnd[0], r1 = bnd[1];
  for (int r = r0 + wv; r < r1; r += 16) {
    const int kl = kposl[r] - 32*b;
    const float ret = se1[r]*(utot - (base_u + pu[kl][lane]))
                    + se1s[r]*(base_v + pv[kl][lane]);
    out[(size_t)inv1[r]*OO + lane] = (ret > 0.f) ? ret : expm1f(ret);
  }
  }  // rep
}

extern "C" void kernel_launch(void* const* d_in, const int* in_sizes, int n_in,
                              void* d_out, int out_size, void* d_ws, size_t ws_size,
                              hipStream_t stream)
{
  (void)in_sizes; (void)n_in; (void)out_size; (void)ws_size;
  const float* x   = (const float*)d_in[0];
  const float* W1  = (const float*)d_in[1];
  const float* b1  = (const float*)d_in[2];
  const float* a1  = (const float*)d_in[3];
  const float* ba1 = (const float*)d_in[4];
  const float* a2  = (const float*)d_in[5];
  const float* ba2 = (const float*)d_in[6];
  float* out = (float*)d_out;

  float* w = (float*)d_ws;
  size_t off = 0;
  auto alloc = [&](size_t n) { float* p = w + off; off += (n + 63) & ~(size_t)63; return p; };
  float* seq  = alloc((size_t)NN*OO);
  float* f1   = alloc(NN);
  float* f2   = alloc(NN);
  float* E1   = alloc(NN);
  float* E1s  = alloc(NN);
  float* eF2  = alloc(NN);
  float* eF2s = alloc(NN);
  unsigned long long* keys = (unsigned long long*)alloc((size_t)4*NN);
  int*   inv1 = (int*)alloc(NN);
  int*   inv  = (int*)alloc(NN);
  float* s1   = alloc(NN);
  float* se1  = alloc(NN);
  float* se1s = alloc(NN);
  float* f2s  = alloc(NN);
  float* eF2srt  = alloc(NN);
  float* eF2ssrt = alloc(NN);
  float* Bs   = alloc(NN);
  float* Es   = alloc(NN);
  int*   kpos = (int*)alloc(NN);
  float* TU   = alloc(256*64);
  float* TV   = alloc(256*64);

  k_gemm<<<512, 256, 0, stream>>>(x, W1, b1, a1, ba1, a2, ba2,
                                  seq, f1, f2, E1, E1s, eF2, eF2s, keys);
  k_rank<<<256, 512, 0, stream>>>(keys, f1, E1, E1s, f2, eF2, eF2s,
                                  s1, se1, se1s, inv1, f2s, eF2srt, eF2ssrt, inv);
  k_DT<<<256, 1024, 0, stream>>>(se1, se1s, s1, f2s, eF2srt, eF2ssrt,
                                 inv, seq, Bs, Es, kpos, TU, TV);
  k_merge<<<256, 1024, 0, stream>>>(kpos, inv, inv1, se1, se1s, Bs, Es,
                                    seq, TU, TV, out);
}

// Round 15
// 55.296 us; speedup vs baseline: 6.9914x; 6.9914x over previous
//
#include <hip/hip_runtime.h>
#include <math.h>

#define NN 8192
#define CC 256
#define OO 64
#define JW 8      // j's per wave in k_rank

// ============ K1: split-K GEMM partials. grid (512, 2): 16 rows x 128-c half each ============
__global__ __launch_bounds__(256) void k_gemm(
    const float* __restrict__ x, const float* __restrict__ W1,
    float* __restrict__ seqp /* [2][NN][OO] */)
{
  __shared__ float w_lds[64][66];    // 16.5 KB
  __shared__ float x_lds[16][128];   // 8 KB
  const int t = threadIdx.x;
  const int p = t & 31;              // col pair: o = 2p, 2p+1
  const int g = t >> 5;              // 0..7 row group (2 rows each)
  const int bx = blockIdx.x, h = blockIdx.y;
  const int r0 = bx*16 + g*2;
  const int r1 = r0 + 1;
  // stage 16 x-rows x 128 cols (coalesced)
  for (int q = t; q < 512; q += 256) {
    const int row = q >> 5, c4 = q & 31;
    ((float4*)x_lds[row])[c4] =
        ((const float4*)(x + (size_t)(bx*16 + row)*CC + h*128))[c4];
  }
  float c00 = 0.f, c01 = 0.f, c10 = 0.f, c11 = 0.f;
  for (int ct = 0; ct < 2; ++ct) {
    __syncthreads();
    for (int idx = t; idx < 4096; idx += 256) {
      const int o = idx >> 6, cc = idx & 63;
      w_lds[cc][o] = W1[o*CC + h*128 + ct*64 + cc];
    }
    __syncthreads();
    const float* xr0 = &x_lds[g*2][ct*64];
    const float* xr1 = &x_lds[g*2+1][ct*64];
#pragma unroll 4
    for (int c = 0; c < 64; c += 4) {
      const float4 xa = *(const float4*)(xr0 + c);
      const float4 xb = *(const float4*)(xr1 + c);
      const float2 w0 = *(const float2*)&w_lds[c+0][2*p];
      const float2 w1 = *(const float2*)&w_lds[c+1][2*p];
      const float2 w2 = *(const float2*)&w_lds[c+2][2*p];
      const float2 w3 = *(const float2*)&w_lds[c+3][2*p];
      c00 = fmaf(xa.x, w0.x, c00); c00 = fmaf(xa.y, w1.x, c00);
      c00 = fmaf(xa.z, w2.x, c00); c00 = fmaf(xa.w, w3.x, c00);
      c01 = fmaf(xa.x, w0.y, c01); c01 = fmaf(xa.y, w1.y, c01);
      c01 = fmaf(xa.z, w2.y, c01); c01 = fmaf(xa.w, w3.y, c01);
      c10 = fmaf(xb.x, w0.x, c10); c10 = fmaf(xb.y, w1.x, c10);
      c10 = fmaf(xb.z, w2.x, c10); c10 = fmaf(xb.w, w3.x, c10);
      c11 = fmaf(xb.x, w0.y, c11); c11 = fmaf(xb.y, w1.y, c11);
      c11 = fmaf(xb.z, w2.y, c11); c11 = fmaf(xb.w, w3.y, c11);
    }
  }
  float* dst = seqp + (size_t)h*NN*OO;
  *(float2*)&dst[(size_t)r0*OO + 2*p] = make_float2(c00, c01);
  *(float2*)&dst[(size_t)r1*OO + 2*p] = make_float2(c10, c11);
}

// ============ K2: sum partials + bias -> seq; f1/f2 reductions; exp tables; keys ============
// grid 2048 x 256: one wave per row
__global__ __launch_bounds__(256) void k_fsum(
    const float* __restrict__ seqp, const float* __restrict__ b1,
    const float* __restrict__ a1, const float* __restrict__ ba1,
    const float* __restrict__ a2, const float* __restrict__ ba2,
    float* __restrict__ seq,
    float* __restrict__ f1, float* __restrict__ f2,
    float* __restrict__ E1, float* __restrict__ E1s,
    float* __restrict__ eF2, float* __restrict__ eF2s,
    unsigned long long* __restrict__ keys)
{
  const int lane = threadIdx.x & 63;
  const int i = blockIdx.x*4 + (threadIdx.x >> 6);
  const float s = seqp[(size_t)i*OO + lane]
                + seqp[(size_t)(NN + i)*OO + lane] + b1[lane];
  seq[(size_t)i*OO + lane] = s;
  float p1 = s * a1[lane];
  float p2 = s * a2[lane];
#pragma unroll
  for (int d = 1; d < 64; d <<= 1) {
    p1 += __shfl_xor(p1, d, 64);
    p2 += __shfl_xor(p2, d, 64);
  }
  if (lane == 0) {
    const float t1 = p1 + ba1[0], t2 = p2 + ba2[0];
    f1[i] = t1; E1[i] = expf(t1); E1s[i] = expf(0.01f*t1);
    f2[i] = t2; eF2[i] = expf(t2); eF2s[i] = expf(0.01f*t2);
    unsigned u;
    u = __float_as_uint(t1); u = (u & 0x80000000u) ? ~u : (u | 0x80000000u);
    keys[i] = ((unsigned long long)u << 32) | (unsigned)i;
    u = __float_as_uint(t2); u = (u & 0x80000000u) ? ~u : (u | 0x80000000u);
    keys[NN + i] = ((unsigned long long)u << 32) | (unsigned)i;
  }
}

// ============ K3: rank partial counts, half the keys per block. grid (256, 2) ============
__global__ __launch_bounds__(512) void k_rank(
    const unsigned long long* __restrict__ keys, int* __restrict__ pCnt)
{
  __shared__ unsigned long long skl[NN/2];   // 32 KB
  const int t = threadIdx.x;
  const int lane = t & 63, wv = t >> 6;      // 8 waves
  const int bx = blockIdx.x, kh = blockIdx.y;
  const int arr = bx >> 7;                   // 0: f1 keys, 1: f2 keys
  const int jbw = (bx & 127)*64 + wv*JW;     // this wave's 8 j's
  const unsigned long long* kb = keys + ((size_t)arr << 13);
  for (int q = t; q < NN/4; q += 512)
    ((ulonglong2*)skl)[q] = ((const ulonglong2*)(kb + kh*(NN/2)))[q];
  __syncthreads();
  unsigned long long K[JW];
#pragma unroll
  for (int q = 0; q < JW; ++q) {
    const unsigned long long kk = kb[jbw + q];   // uniform global load (8/wave)
    const unsigned lo = __builtin_amdgcn_readfirstlane((unsigned)kk);
    const unsigned hi = __builtin_amdgcn_readfirstlane((unsigned)(kk >> 32));
    K[q] = ((unsigned long long)hi << 32) | lo;
  }
  int cnt[JW];
#pragma unroll
  for (int q = 0; q < JW; ++q) cnt[q] = 0;
#pragma unroll 4
  for (int c = 0; c < NN/128; ++c) {           // 64 iters over half the keys
    const unsigned long long sk = skl[c*64 + lane];
#pragma unroll
    for (int q = 0; q < JW; ++q)
      cnt[q] += (sk < K[q]) ? 1 : 0;
  }
#pragma unroll
  for (int q = 0; q < JW; ++q) {
    int r = cnt[q];
#pragma unroll
    for (int d = 1; d < 64; d <<= 1) r += __shfl_xor(r, d, 64);
    if (lane == 0)
      pCnt[(size_t)(arr*2 + kh)*NN + jbw + q] = r;
  }
}

// ============ K4: combine rank partials + sorted scatters. grid 32 x 512 ============
__global__ __launch_bounds__(512) void k_scat(
    const int* __restrict__ pCnt,
    const float* __restrict__ f1, const float* __restrict__ E1,
    const float* __restrict__ E1s, const float* __restrict__ f2,
    const float* __restrict__ eF2, const float* __restrict__ eF2s,
    float* __restrict__ s1, float* __restrict__ se1, float* __restrict__ se1s,
    int* __restrict__ inv1,
    float* __restrict__ f2s, float* __restrict__ eF2srt,
    float* __restrict__ eF2ssrt, int* __restrict__ inv)
{
  const int u = blockIdx.x*512 + threadIdx.x;   // 0..16383
  const int arr = u >> 13, j = u & (NN-1);
  const int r = pCnt[(size_t)(arr*2)*NN + j] + pCnt[(size_t)(arr*2+1)*NN + j];
  if (arr == 0) {
    s1[r] = f1[j]; se1[r] = E1[j]; se1s[r] = E1s[j]; inv1[r] = j;
  } else {
    inv[r] = j; f2s[r] = f2[j]; eF2srt[r] = eF2[j]; eF2ssrt[r] = eF2s[j];
  }
}

// ============ K5: D-factors + kpos (LDS bsearch) + TU/TV chunk totals ============
__global__ __launch_bounds__(1024) void k_DT(
    const float* __restrict__ se1, const float* __restrict__ se1s,
    const float* __restrict__ s1g,
    const float* __restrict__ f2s, const float* __restrict__ eF2srt,
    const float* __restrict__ eF2ssrt, const int* __restrict__ inv,
    const float* __restrict__ seq,
    float* __restrict__ Bs, float* __restrict__ Es,
    int* __restrict__ kpos, float* __restrict__ TU, float* __restrict__ TV)
{
  __shared__ float s1l[NN];          // 32 KB (sorted f1)
  __shared__ float f2sl[NN];         // 32 KB (sorted f2)
  __shared__ float csA[256], csB[256];
  __shared__ float csEA[257], csEB[257];
  __shared__ float wsA[4], wsB[4];
  __shared__ float bsl[32], esl[32];
  __shared__ float redU[16][64], redV[16][64];
  const int t = threadIdx.x;
  const int b = blockIdx.x;
  const int wv = t >> 6, lane = t & 63;
  const float4 a0 = ((const float4*)se1 )[t*2];
  const float4 a1v = ((const float4*)se1 )[t*2+1];
  const float4 b0 = ((const float4*)se1s)[t*2];
  const float4 b1v = ((const float4*)se1s)[t*2+1];
  ((float4*)s1l)[t*2]   = ((const float4*)s1g)[t*2];
  ((float4*)s1l)[t*2+1] = ((const float4*)s1g)[t*2+1];
  ((float4*)f2sl)[t*2]   = ((const float4*)f2s)[t*2];
  ((float4*)f2sl)[t*2+1] = ((const float4*)f2s)[t*2+1];
  float sa = ((a0.x+a0.y)+(a0.z+a0.w)) + ((a1v.x+a1v.y)+(a1v.z+a1v.w));
  float sb = ((b0.x+b0.y)+(b0.z+b0.w)) + ((b1v.x+b1v.y)+(b1v.z+b1v.w));
  sa += __shfl_xor(sa, 1, 64); sb += __shfl_xor(sb, 1, 64);
  sa += __shfl_xor(sa, 2, 64); sb += __shfl_xor(sb, 2, 64);
  if ((t & 3) == 0) { csA[t>>2] = sa; csB[t>>2] = sb; }   // chunk(32) sums
  __syncthreads();
  // 4-wave shfl scan of 256 chunk sums
  if (t < 256) {
    float a = csA[t], bv = csB[t];
#pragma unroll
    for (int d = 1; d < 64; d <<= 1) {
      const float ua = __shfl_up(a, d, 64);
      const float ub = __shfl_up(bv, d, 64);
      if (lane >= d) { a += ua; bv += ub; }
    }
    csA[t] = a; csB[t] = bv;
    if (lane == 63) { wsA[wv] = a; wsB[wv] = bv; }
  }
  __syncthreads();
  if (t < 256) {
    float baseA = 0.f, baseB = 0.f;
    for (int q = 0; q < wv; ++q) { baseA += wsA[q]; baseB += wsB[q]; }
    csEA[t+1] = csA[t] + baseA;
    csEB[t+1] = csB[t] + baseB;
    if (t == 0) { csEA[0] = 0.f; csEB[0] = 0.f; }
  }
  __syncthreads();
  const int half = lane >> 5, m = lane & 31;
  // --- D part ---
  {
    const int kk = b*32 + 2*wv + half;
    const float tgt = -f2sl[kk];
    int pos = 0;
#pragma unroll
    for (int s = NN; s; s >>= 1) {
      const int c = pos + s;
      if (c <= NN && s1l[c-1] < tgt) pos = c;
    }
    const int base = pos & ~31, cn = pos & 31;
    float ta = 0.f, tb = 0.f;
    if (m < cn) { ta = se1[base+m]; tb = se1s[base+m]; }
#pragma unroll
    for (int d = 1; d < 32; d <<= 1) {
      ta += __shfl_xor(ta, d, 64);
      tb += __shfl_xor(tb, d, 64);
    }
    if (m == 0) {
      const float PreA = csEA[pos>>5] + ta;
      const float PreB = csEB[pos>>5] + tb;
      const float T1 = csEA[256];
      const float e2 = eF2srt[kk], e2s = eF2ssrt[kk];
      const float D = fmaf(T1 - PreA, e2, PreB * e2s);
      const float bsv = e2 / D, esv = e2s / D;
      Bs[kk] = bsv; Es[kk] = esv;
      bsl[2*wv + half] = bsv; esl[2*wv + half] = esv;
    }
  }
  // --- kpos: kpos[r] = #{ f2 < -s1[r] } via binary search in LDS sorted f2 ---
  if (t < 32) {
    const int r = b*32 + t;
    const float tgt = -s1l[r];
    int pos = 0;
#pragma unroll
    for (int s = NN; s; s >>= 1) {
      const int c = pos + s;
      if (c <= NN && f2sl[c-1] < tgt) pos = c;
    }
    kpos[r] = pos;
  }
  __syncthreads();
  // --- TU/TV: chunk b column totals from LDS factors ---
  {
    const int kk0 = b*32 + 2*wv, kk1 = kk0 + 1;
    const float s0v = seq[(size_t)inv[kk0]*OO + lane];
    const float s1v = seq[(size_t)inv[kk1]*OO + lane];
    redU[wv][lane] = bsl[2*wv]*s0v + bsl[2*wv+1]*s1v;
    redV[wv][lane] = esl[2*wv]*s0v + esl[2*wv+1]*s1v;
  }
  __syncthreads();
  if (wv == 0) {
    float r = 0.f;
#pragma unroll
    for (int q = 0; q < 16; ++q) r += redU[q][lane];
    TU[b*64 + lane] = r;
  } else if (wv == 1) {
    float r = 0.f;
#pragma unroll
    for (int q = 0; q < 16; ++q) r += redV[q][lane];
    TV[b*64 + lane] = r;
  }
}

// ============ K6: merged prefix + output (no PU/PV tables), 1024 threads ============
__global__ __launch_bounds__(1024) void k_merge(
    const int* __restrict__ kpos, const int* __restrict__ inv,
    const int* __restrict__ inv1,
    const float* __restrict__ se1, const float* __restrict__ se1s,
    const float* __restrict__ Bs, const float* __restrict__ Es,
    const float* __restrict__ seq,
    const float* __restrict__ TU, const float* __restrict__ TV,
    float* __restrict__ out)
{
  __shared__ int kposl[NN];                    // 32 KB
  __shared__ float pu[33][64], pv[33][64];     // 16.5 KB
  __shared__ float rA[16][64], rB[16][64], rC[16][64];
  __shared__ int bnd[2];
  const int t = threadIdx.x, lane = t & 63, wv = t >> 6, b = blockIdx.x;
  for (int q = t; q < NN/4; q += 1024)
    ((int4*)kposl)[q] = ((const int4*)kpos)[q];
  // base (chunks < b) and grand total of TU; base of TV — split over 16 waves
  float pbu = 0.f, pbv = 0.f, ptu = 0.f;
  for (int c = wv; c < 256; c += 16) {
    const float tu = TU[c*64 + lane], tv = TV[c*64 + lane];
    ptu += tu;
    if (c < b) { pbu += tu; pbv += tv; }
  }
  rA[wv][lane] = pbu; rB[wv][lane] = pbv; rC[wv][lane] = ptu;
  // stage scaled rows (16 waves x 2 rows, parallel gathers)
  {
    const int kk0 = b*32 + 2*wv, kk1 = kk0 + 1;
    const float sv0 = seq[(size_t)inv[kk0]*OO + lane];
    const float sv1 = seq[(size_t)inv[kk1]*OO + lane];
    pu[2*wv+1][lane] = Bs[kk0]*sv0; pv[2*wv+1][lane] = Es[kk0]*sv0;
    pu[2*wv+2][lane] = Bs[kk1]*sv1; pv[2*wv+2][lane] = Es[kk1]*sv1;
  }
  if (wv == 0) { pu[0][lane] = 0.f; pv[0][lane] = 0.f; }
  __syncthreads();
  if (t == 0) {   // emit range boundaries in descending kposl
    const int hi = 32*b + 32 + (b == 255 ? 1 : 0);
    int pos = 0;
    for (int s = NN; s; s >>= 1) { const int c = pos+s; if (c <= NN && kposl[c-1] >= hi) pos = c; }
    bnd[0] = pos;
    pos = 0;
    const int lo = 32*b;
    for (int s = NN; s; s >>= 1) { const int c = pos+s; if (c <= NN && kposl[c-1] >= lo) pos = c; }
    bnd[1] = pos;
  }
  float base_u = 0.f, base_v = 0.f, utot = 0.f;
#pragma unroll
  for (int q = 0; q < 16; ++q) {
    base_u += rA[q][lane]; base_v += rB[q][lane]; utot += rC[q][lane];
  }
  // Hillis-Steele over rows 1..32 (2 rows per thread-slice)
  for (int d = 1; d < 32; d <<= 1) {
    const int rowA = wv + 1;        // rows 1..16
    const int rowB = wv + 17;       // rows 17..32
    const int srcA = rowA - d, srcB = rowB - d;
    const float aA = (srcA >= 0) ? pu[srcA][lane] : 0.f;
    const float vA = (srcA >= 0) ? pv[srcA][lane] : 0.f;
    const float aB = (srcB >= 0) ? pu[srcB][lane] : 0.f;
    const float vB = (srcB >= 0) ? pv[srcB][lane] : 0.f;
    __syncthreads();
    pu[rowA][lane] += aA; pv[rowA][lane] += vA;
    pu[rowB][lane] += aB; pv[rowB][lane] += vB;
    __syncthreads();
  }
  // parallel emits
  const int r0 = bnd[0], r1 = bnd[1];
  for (int r = r0 + wv; r < r1; r += 16) {
    const int kl = kposl[r] - 32*b;
    const float ret = se1[r]*(utot - (base_u + pu[kl][lane]))
                    + se1s[r]*(base_v + pv[kl][lane]);
    out[(size_t)inv1[r]*OO + lane] = (ret > 0.f) ? ret : expm1f(ret);
  }
}

extern "C" void kernel_launch(void* const* d_in, const int* in_sizes, int n_in,
                              void* d_out, int out_size, void* d_ws, size_t ws_size,
                              hipStream_t stream)
{
  (void)in_sizes; (void)n_in; (void)out_size; (void)ws_size;
  const float* x   = (const float*)d_in[0];
  const float* W1  = (const float*)d_in[1];
  const float* b1  = (const float*)d_in[2];
  const float* a1  = (const float*)d_in[3];
  const float* ba1 = (const float*)d_in[4];
  const float* a2  = (const float*)d_in[5];
  const float* ba2 = (const float*)d_in[6];
  float* out = (float*)d_out;

  float* w = (float*)d_ws;
  size_t off = 0;
  auto alloc = [&](size_t n) { float* p = w + off; off += (n + 63) & ~(size_t)63; return p; };
  float* seqp = alloc((size_t)2*NN*OO);
  float* seq  = alloc((size_t)NN*OO);
  float* f1   = alloc(NN);
  float* f2   = alloc(NN);
  float* E1   = alloc(NN);
  float* E1s  = alloc(NN);
  float* eF2  = alloc(NN);
  float* eF2s = alloc(NN);
  unsigned long long* keys = (unsigned long long*)alloc((size_t)4*NN);
  int*   pCnt = (int*)alloc((size_t)4*NN);
  int*   inv1 = (int*)alloc(NN);
  int*   inv  = (int*)alloc(NN);
  float* s1   = alloc(NN);
  float* se1  = alloc(NN);
  float* se1s = alloc(NN);
  float* f2s  = alloc(NN);
  float* eF2srt  = alloc(NN);
  float* eF2ssrt = alloc(NN);
  float* Bs   = alloc(NN);
  float* Es   = alloc(NN);
  int*   kpos = (int*)alloc(NN);
  float* TU   = alloc(256*64);
  float* TV   = alloc(256*64);

  k_gemm<<<dim3(512, 2), 256, 0, stream>>>(x, W1, seqp);
  k_fsum<<<2048, 256, 0, stream>>>(seqp, b1, a1, ba1, a2, ba2,
                                   seq, f1, f2, E1, E1s, eF2, eF2s, keys);
  k_rank<<<dim3(256, 2), 512, 0, stream>>>(keys, pCnt);
  k_scat<<<32, 512, 0, stream>>>(pCnt, f1, E1, E1s, f2, eF2, eF2s,
                                 s1, se1, se1s, inv1, f2s, eF2srt, eF2ssrt, inv);
  k_DT<<<256, 1024, 0, stream>>>(se1, se1s, s1, f2s, eF2srt, eF2ssrt,
                                 inv, seq, Bs, Es, kpos, TU, TV);
  k_merge<<<256, 1024, 0, stream>>>(kpos, inv, inv1, se1, se1s, Bs, Es,
                                    seq, TU, TV, out);
}

// Round 16
// 54.288 us; speedup vs baseline: 7.1213x; 1.0186x over previous
//
#include <hip/hip_runtime.h>
#include <math.h>

#define NN 8192
#define CC 256
#define OO 64
#define JW 4      // j's per wave in k_rank

// ============ K1: GEMM, 8 rows/block, grid 1024 (4 blocks/CU) ============
__global__ __launch_bounds__(256) void k_gemm(
    const float* __restrict__ x, const float* __restrict__ W1,
    const float* __restrict__ b1, const float* __restrict__ a1,
    const float* __restrict__ ba1, const float* __restrict__ a2,
    const float* __restrict__ ba2,
    float* __restrict__ seq,
    float* __restrict__ f1, float* __restrict__ f2,
    float* __restrict__ E1, float* __restrict__ E1s,
    float* __restrict__ eF2, float* __restrict__ eF2s,
    unsigned long long* __restrict__ keys /* [2][NN] */)
{
  __shared__ float w_lds[64][66];    // 16.9 KB
  __shared__ float x_lds[8][256];    // 8 KB
  const int t = threadIdx.x;
  const int p = t & 31;              // col pair: o = 2p, 2p+1
  const int row = t >> 5;            // 0..7
  const int r = blockIdx.x*8 + row;
  // stage 8 x-rows (coalesced): 512 float4
  for (int q = t; q < 512; q += 256) {
    const int rr = q >> 6, c4 = q & 63;
    ((float4*)x_lds[rr])[c4] = ((const float4*)(x + (size_t)(blockIdx.x*8 + rr)*CC))[c4];
  }
  float c0 = 0.f, c1 = 0.f;
  for (int ct = 0; ct < 4; ++ct) {
    __syncthreads();
    for (int idx = t; idx < 4096; idx += 256) {
      const int o = idx >> 6, cc = idx & 63;
      w_lds[cc][o] = W1[o*CC + ct*64 + cc];
    }
    __syncthreads();
    const float* xr = &x_lds[row][ct*64];
#pragma unroll 4
    for (int c = 0; c < 64; c += 4) {
      const float4 xa = *(const float4*)(xr + c);
      const float2 w0 = *(const float2*)&w_lds[c+0][2*p];
      const float2 w1 = *(const float2*)&w_lds[c+1][2*p];
      const float2 w2 = *(const float2*)&w_lds[c+2][2*p];
      const float2 w3 = *(const float2*)&w_lds[c+3][2*p];
      c0 = fmaf(xa.x, w0.x, c0); c0 = fmaf(xa.y, w1.x, c0);
      c0 = fmaf(xa.z, w2.x, c0); c0 = fmaf(xa.w, w3.x, c0);
      c1 = fmaf(xa.x, w0.y, c1); c1 = fmaf(xa.y, w1.y, c1);
      c1 = fmaf(xa.z, w2.y, c1); c1 = fmaf(xa.w, w3.y, c1);
    }
  }
  const float2 B2 = *(const float2*)&b1[2*p];
  const float v0 = c0 + B2.x, v1 = c1 + B2.y;
  *(float2*)&seq[(size_t)r*OO + 2*p] = make_float2(v0, v1);
  const float2 A1 = *(const float2*)&a1[2*p];
  const float2 A2 = *(const float2*)&a2[2*p];
  float p1 = v0*A1.x + v1*A1.y;
  float p2 = v0*A2.x + v1*A2.y;
  // reduce within 32-lane half (one row per half-wave)
#pragma unroll
  for (int d = 1; d < 32; d <<= 1) {
    p1 += __shfl_xor(p1, d, 64);
    p2 += __shfl_xor(p2, d, 64);
  }
  if (p == 0) {
    const float t1 = p1 + ba1[0], t2 = p2 + ba2[0];
    f1[r] = t1; E1[r] = expf(t1); E1s[r] = expf(0.01f*t1);
    f2[r] = t2; eF2[r] = expf(t2); eF2s[r] = expf(0.01f*t2);
    unsigned u;
    u = __float_as_uint(t1); u = (u & 0x80000000u) ? ~u : (u | 0x80000000u);
    keys[r] = ((unsigned long long)u << 32) | (unsigned)r;
    u = __float_as_uint(t2); u = (u & 0x80000000u) ? ~u : (u | 0x80000000u);
    keys[NN + r] = ((unsigned long long)u << 32) | (unsigned)r;
  }
}

// ============ K2: rank counting, 32 j's/block, grid 512 (2 blocks/CU) ============
__global__ __launch_bounds__(512) void k_rank(
    const unsigned long long* __restrict__ keys,
    const float* __restrict__ f1, const float* __restrict__ E1,
    const float* __restrict__ E1s, const float* __restrict__ f2,
    const float* __restrict__ eF2, const float* __restrict__ eF2s,
    float* __restrict__ s1, float* __restrict__ se1, float* __restrict__ se1s,
    int* __restrict__ inv1,
    float* __restrict__ f2s, float* __restrict__ eF2srt,
    float* __restrict__ eF2ssrt, int* __restrict__ inv)
{
  __shared__ unsigned long long skl[NN];   // 64 KB
  const int t = threadIdx.x;
  const int lane = t & 63, wv = t >> 6;    // 8 waves
  const int b = blockIdx.x;
  const int arr = b >> 8;                  // 0: f1 keys (b<256), 1: f2 keys
  const int jbw = (b & 255)*32 + wv*JW;    // this wave's 4 j's
  const unsigned long long* kb = keys + ((size_t)arr << 13);
  for (int q = t; q < NN/2; q += 512)
    ((ulonglong2*)skl)[q] = ((const ulonglong2*)kb)[q];
  __syncthreads();
  unsigned long long K[JW];
#pragma unroll
  for (int q = 0; q < JW; ++q) {
    const unsigned long long kk = skl[jbw + q];   // wave-uniform LDS addr -> broadcast
    const unsigned lo = __builtin_amdgcn_readfirstlane((unsigned)kk);
    const unsigned hi = __builtin_amdgcn_readfirstlane((unsigned)(kk >> 32));
    K[q] = ((unsigned long long)hi << 32) | lo;
  }
  int cnt[JW];
#pragma unroll
  for (int q = 0; q < JW; ++q) cnt[q] = 0;
#pragma unroll 4
  for (int c = 0; c < NN/64; ++c) {
    const unsigned long long sk = skl[c*64 + lane];   // per-lane, conflict-free
#pragma unroll
    for (int q = 0; q < JW; ++q)
      cnt[q] += (sk < K[q]) ? 1 : 0;
  }
#pragma unroll
  for (int q = 0; q < JW; ++q) {
    int r = cnt[q];
#pragma unroll
    for (int d = 1; d < 64; d <<= 1) r += __shfl_xor(r, d, 64);
    if (lane == 0) {
      const int i = jbw + q;
      if (arr == 0) {
        s1[r] = f1[i]; se1[r] = E1[i]; se1s[r] = E1s[i]; inv1[r] = i;
      } else {
        inv[r] = i; f2s[r] = f2[i]; eF2srt[r] = eF2[i]; eF2ssrt[r] = eF2s[i];
      }
    }
  }
}

// ============ K3: D-factors + kpos (LDS bsearch) + TU/TV chunk totals ============
__global__ __launch_bounds__(1024) void k_DT(
    const float* __restrict__ se1, const float* __restrict__ se1s,
    const float* __restrict__ s1g,
    const float* __restrict__ f2s, const float* __restrict__ eF2srt,
    const float* __restrict__ eF2ssrt, const int* __restrict__ inv,
    const float* __restrict__ seq,
    float* __restrict__ Bs, float* __restrict__ Es,
    int* __restrict__ kpos, float* __restrict__ TU, float* __restrict__ TV)
{
  __shared__ float s1l[NN];          // 32 KB (sorted f1)
  __shared__ float f2sl[NN];         // 32 KB (sorted f2)
  __shared__ float csA[256], csB[256];
  __shared__ float csEA[257], csEB[257];
  __shared__ float wsA[4], wsB[4];
  __shared__ float bsl[32], esl[32];
  __shared__ float redU[16][64], redV[16][64];
  const int t = threadIdx.x;
  const int b = blockIdx.x;
  const int wv = t >> 6, lane = t & 63;
  const float4 a0 = ((const float4*)se1 )[t*2];
  const float4 a1v = ((const float4*)se1 )[t*2+1];
  const float4 b0 = ((const float4*)se1s)[t*2];
  const float4 b1v = ((const float4*)se1s)[t*2+1];
  ((float4*)s1l)[t*2]   = ((const float4*)s1g)[t*2];
  ((float4*)s1l)[t*2+1] = ((const float4*)s1g)[t*2+1];
  ((float4*)f2sl)[t*2]   = ((const float4*)f2s)[t*2];
  ((float4*)f2sl)[t*2+1] = ((const float4*)f2s)[t*2+1];
  float sa = ((a0.x+a0.y)+(a0.z+a0.w)) + ((a1v.x+a1v.y)+(a1v.z+a1v.w));
  float sb = ((b0.x+b0.y)+(b0.z+b0.w)) + ((b1v.x+b1v.y)+(b1v.z+b1v.w));
  sa += __shfl_xor(sa, 1, 64); sb += __shfl_xor(sb, 1, 64);
  sa += __shfl_xor(sa, 2, 64); sb += __shfl_xor(sb, 2, 64);
  if ((t & 3) == 0) { csA[t>>2] = sa; csB[t>>2] = sb; }   // chunk(32) sums
  __syncthreads();
  // 4-wave shfl scan of 256 chunk sums
  if (t < 256) {
    float a = csA[t], bv = csB[t];
#pragma unroll
    for (int d = 1; d < 64; d <<= 1) {
      const float ua = __shfl_up(a, d, 64);
      const float ub = __shfl_up(bv, d, 64);
      if (lane >= d) { a += ua; bv += ub; }
    }
    csA[t] = a; csB[t] = bv;
    if (lane == 63) { wsA[wv] = a; wsB[wv] = bv; }
  }
  __syncthreads();
  if (t < 256) {
    float baseA = 0.f, baseB = 0.f;
    for (int q = 0; q < wv; ++q) { baseA += wsA[q]; baseB += wsB[q]; }
    csEA[t+1] = csA[t] + baseA;
    csEB[t+1] = csB[t] + baseB;
    if (t == 0) { csEA[0] = 0.f; csEB[0] = 0.f; }
  }
  __syncthreads();
  const int half = lane >> 5, m = lane & 31;
  // --- D part ---
  {
    const int kk = b*32 + 2*wv + half;
    const float tgt = -f2sl[kk];
    int pos = 0;
#pragma unroll
    for (int s = NN; s; s >>= 1) {
      const int c = pos + s;
      if (c <= NN && s1l[c-1] < tgt) pos = c;
    }
    const int base = pos & ~31, cn = pos & 31;
    float ta = 0.f, tb = 0.f;
    if (m < cn) { ta = se1[base+m]; tb = se1s[base+m]; }
#pragma unroll
    for (int d = 1; d < 32; d <<= 1) {
      ta += __shfl_xor(ta, d, 64);
      tb += __shfl_xor(tb, d, 64);
    }
    if (m == 0) {
      const float PreA = csEA[pos>>5] + ta;
      const float PreB = csEB[pos>>5] + tb;
      const float T1 = csEA[256];
      const float e2 = eF2srt[kk], e2s = eF2ssrt[kk];
      const float D = fmaf(T1 - PreA, e2, PreB * e2s);
      const float bsv = e2 / D, esv = e2s / D;
      Bs[kk] = bsv; Es[kk] = esv;
      bsl[2*wv + half] = bsv; esl[2*wv + half] = esv;
    }
  }
  // --- kpos: kpos[r] = #{ f2 < -s1[r] } via binary search in LDS sorted f2 ---
  if (t < 32) {
    const int r = b*32 + t;
    const float tgt = -s1l[r];
    int pos = 0;
#pragma unroll
    for (int s = NN; s; s >>= 1) {
      const int c = pos + s;
      if (c <= NN && f2sl[c-1] < tgt) pos = c;
    }
    kpos[r] = pos;
  }
  __syncthreads();
  // --- TU/TV: chunk b column totals from LDS factors ---
  {
    const int kk0 = b*32 + 2*wv, kk1 = kk0 + 1;
    const float s0v = seq[(size_t)inv[kk0]*OO + lane];
    const float s1v = seq[(size_t)inv[kk1]*OO + lane];
    redU[wv][lane] = bsl[2*wv]*s0v + bsl[2*wv+1]*s1v;
    redV[wv][lane] = esl[2*wv]*s0v + esl[2*wv+1]*s1v;
  }
  __syncthreads();
  if (wv == 0) {
    float r = 0.f;
#pragma unroll
    for (int q = 0; q < 16; ++q) r += redU[q][lane];
    TU[b*64 + lane] = r;
  } else if (wv == 1) {
    float r = 0.f;
#pragma unroll
    for (int q = 0; q < 16; ++q) r += redV[q][lane];
    TV[b*64 + lane] = r;
  }
}

// ============ K4: merged prefix + output (no PU/PV tables), 1024 threads ============
__global__ __launch_bounds__(1024) void k_merge(
    const int* __restrict__ kpos, const int* __restrict__ inv,
    const int* __restrict__ inv1,
    const float* __restrict__ se1, const float* __restrict__ se1s,
    const float* __restrict__ Bs, const float* __restrict__ Es,
    const float* __restrict__ seq,
    const float* __restrict__ TU, const float* __restrict__ TV,
    float* __restrict__ out)
{
  __shared__ int kposl[NN];                    // 32 KB
  __shared__ float pu[33][64], pv[33][64];     // 16.5 KB
  __shared__ float rA[16][64], rB[16][64], rC[16][64];
  __shared__ int bnd[2];
  const int t = threadIdx.x, lane = t & 63, wv = t >> 6, b = blockIdx.x;
  for (int q = t; q < NN/4; q += 1024)
    ((int4*)kposl)[q] = ((const int4*)kpos)[q];
  // base (chunks < b) and grand total of TU; base of TV — split over 16 waves
  float pbu = 0.f, pbv = 0.f, ptu = 0.f;
  for (int c = wv; c < 256; c += 16) {
    const float tu = TU[c*64 + lane], tv = TV[c*64 + lane];
    ptu += tu;
    if (c < b) { pbu += tu; pbv += tv; }
  }
  rA[wv][lane] = pbu; rB[wv][lane] = pbv; rC[wv][lane] = ptu;
  // stage scaled rows (16 waves x 2 rows, parallel gathers)
  {
    const int kk0 = b*32 + 2*wv, kk1 = kk0 + 1;
    const float sv0 = seq[(size_t)inv[kk0]*OO + lane];
    const float sv1 = seq[(size_t)inv[kk1]*OO + lane];
    pu[2*wv+1][lane] = Bs[kk0]*sv0; pv[2*wv+1][lane] = Es[kk0]*sv0;
    pu[2*wv+2][lane] = Bs[kk1]*sv1; pv[2*wv+2][lane] = Es[kk1]*sv1;
  }
  if (wv == 0) { pu[0][lane] = 0.f; pv[0][lane] = 0.f; }
  __syncthreads();
  if (t == 0) {   // emit range boundaries in descending kposl
    const int hi = 32*b + 32 + (b == 255 ? 1 : 0);
    int pos = 0;
    for (int s = NN; s; s >>= 1) { const int c = pos+s; if (c <= NN && kposl[c-1] >= hi) pos = c; }
    bnd[0] = pos;
    pos = 0;
    const int lo = 32*b;
    for (int s = NN; s; s >>= 1) { const int c = pos+s; if (c <= NN && kposl[c-1] >= lo) pos = c; }
    bnd[1] = pos;
  }
  float base_u = 0.f, base_v = 0.f, utot = 0.f;
#pragma unroll
  for (int q = 0; q < 16; ++q) {
    base_u += rA[q][lane]; base_v += rB[q][lane]; utot += rC[q][lane];
  }
  // Hillis-Steele over rows 1..32 (2 rows per thread-slice)
  for (int d = 1; d < 32; d <<= 1) {
    const int rowA = wv + 1;        // rows 1..16
    const int rowB = wv + 17;       // rows 17..32
    const int srcA = rowA - d, srcB = rowB - d;
    const float aA = (srcA >= 0) ? pu[srcA][lane] : 0.f;
    const float vA = (srcA >= 0) ? pv[srcA][lane] : 0.f;
    const float aB = (srcB >= 0) ? pu[srcB][lane] : 0.f;
    const float vB = (srcB >= 0) ? pv[srcB][lane] : 0.f;
    __syncthreads();
    pu[rowA][lane] += aA; pv[rowA][lane] += vA;
    pu[rowB][lane] += aB; pv[rowB][lane] += vB;
    __syncthreads();
  }
  // parallel emits
  const int r0 = bnd[0], r1 = bnd[1];
  for (int r = r0 + wv; r < r1; r += 16) {
    const int kl = kposl[r] - 32*b;
    const float ret = se1[r]*(utot - (base_u + pu[kl][lane]))
                    + se1s[r]*(base_v + pv[kl][lane]);
    out[(size_t)inv1[r]*OO + lane] = (ret > 0.f) ? ret : expm1f(ret);
  }
}

extern "C" void kernel_launch(void* const* d_in, const int* in_sizes, int n_in,
                              void* d_out, int out_size, void* d_ws, size_t ws_size,
                              hipStream_t stream)
{
  (void)in_sizes; (void)n_in; (void)out_size; (void)ws_size;
  const float* x   = (const float*)d_in[0];
  const float* W1  = (const float*)d_in[1];
  const float* b1  = (const float*)d_in[2];
  const float* a1  = (const float*)d_in[3];
  const float* ba1 = (const float*)d_in[4];
  const float* a2  = (const float*)d_in[5];
  const float* ba2 = (const float*)d_in[6];
  float* out = (float*)d_out;

  float* w = (float*)d_ws;
  size_t off = 0;
  auto alloc = [&](size_t n) { float* p = w + off; off += (n + 63) & ~(size_t)63; return p; };
  float* seq  = alloc((size_t)NN*OO);
  float* f1   = alloc(NN);
  float* f2   = alloc(NN);
  float* E1   = alloc(NN);
  float* E1s  = alloc(NN);
  float* eF2  = alloc(NN);
  float* eF2s = alloc(NN);
  unsigned long long* keys = (unsigned long long*)alloc((size_t)4*NN);
  int*   inv1 = (int*)alloc(NN);
  int*   inv  = (int*)alloc(NN);
  float* s1   = alloc(NN);
  float* se1  = alloc(NN);
  float* se1s = alloc(NN);
  float* f2s  = alloc(NN);
  float* eF2srt  = alloc(NN);
  float* eF2ssrt = alloc(NN);
  float* Bs   = alloc(NN);
  float* Es   = alloc(NN);
  int*   kpos = (int*)alloc(NN);
  float* TU   = alloc(256*64);
  float* TV   = alloc(256*64);

  k_gemm<<<1024, 256, 0, stream>>>(x, W1, b1, a1, ba1, a2, ba2,
                                   seq, f1, f2, E1, E1s, eF2, eF2s, keys);
  k_rank<<<512, 512, 0, stream>>>(keys, f1, E1, E1s, f2, eF2, eF2s,
                                  s1, se1, se1s, inv1, f2s, eF2srt, eF2ssrt, inv);
  k_DT<<<256, 1024, 0, stream>>>(se1, se1s, s1, f2s, eF2srt, eF2ssrt,
                                 inv, seq, Bs, Es, kpos, TU, TV);
  k_merge<<<256, 1024, 0, stream>>>(kpos, inv, inv1, se1, se1s, Bs, Es,
                                    seq, TU, TV, out);
}